// Round 4
// baseline (3482.647 us; speedup 1.0000x reference)
//
#include <hip/hip_runtime.h>

typedef unsigned short u16;
typedef _Float16 f16x8_t __attribute__((ext_vector_type(8)));
typedef short    i16x8_t __attribute__((ext_vector_type(8)));
typedef float    f32x4_t __attribute__((ext_vector_type(4)));

// ---- helpers ---------------------------------------------------------------
static __device__ __forceinline__ u16 f2h(float f) {
  _Float16 h = (_Float16)f;  // RNE
  return __builtin_bit_cast(u16, h);
}
static __device__ __forceinline__ float h2f(u16 u) {
  return (float)__builtin_bit_cast(_Float16, u);
}
static __device__ __forceinline__ f32x4_t mfma16h(i16x8_t a, i16x8_t b, f32x4_t c) {
  return __builtin_amdgcn_mfma_f32_16x16x32_f16(
      __builtin_bit_cast(f16x8_t, a), __builtin_bit_cast(f16x8_t, b), c, 0, 0, 0);
}
static __device__ __forceinline__ float sigmoidf_(float x) { return 1.f / (1.f + __expf(-x)); }
static __device__ __forceinline__ float tanhf_(float x) { return 1.f - 2.f / (__expf(2.f * x) + 1.f); }

// ---- prep: LSTM W^T in f16 -------------------------------------------------
// wt: [dir][n=1024][k=384], k<128 -> Wi[k][n], k>=128 -> Wh[k-128][n]
__global__ __launch_bounds__(256) void prep_wt(const float* __restrict__ Wi_f,
                                               const float* __restrict__ Wh_f,
                                               const float* __restrict__ Wi_r,
                                               const float* __restrict__ Wh_r,
                                               u16* __restrict__ wt) {
  int id = blockIdx.x * 256 + threadIdx.x;
  if (id >= 2 * 1024 * 384) return;
  int d = id / (1024 * 384);
  int r = id % (1024 * 384);
  int n = r / 384, k = r % 384;
  const float* Wi = d ? Wi_r : Wi_f;
  const float* Wh = d ? Wh_r : Wh_f;
  float v = (k < 128) ? Wi[k * 1024 + n] : Wh[(k - 128) * 1024 + n];
  wt[id] = f2h(v);
}

// ---- prep: MLP W^T in f16 (TRUE dims: W1[512][256], W2[256][256], W3[256][128])
// w1t: [256][512], w2t: [256][256], w3t: [128][256], all W^T[n][k]
__global__ __launch_bounds__(256) void prep_small(const float* __restrict__ W1,
                                                  const float* __restrict__ W2,
                                                  const float* __restrict__ W3,
                                                  u16* __restrict__ w1t,
                                                  u16* __restrict__ w2t,
                                                  u16* __restrict__ w3t) {
  int id = blockIdx.x * 256 + threadIdx.x;
  if (id < 131072) { int n = id >> 9, k = id & 511; w1t[id] = f2h(W1[k * 256 + n]); return; }
  id -= 131072;
  if (id < 65536) { int n = id >> 8, k = id & 255; w2t[id] = f2h(W2[k * 256 + n]); return; }
  id -= 65536;
  if (id < 32768) { int n = id >> 8, k = id & 255; w3t[id] = f2h(W3[k * 128 + n]); }
}

// ---- bidirectional LSTM (unchanged from round 2 — proven vs fp32) ----------
// grid = 64 blocks: 0..31 forward (16 batch rows each), 32..63 reverse.
// 512 threads = 8 waves; wave wv: gate = wv&3, N-half = wv>>2.
__global__ __launch_bounds__(512, 2) void lstm_kernel(
    const float* __restrict__ x0, const u16* __restrict__ wt,
    const float* __restrict__ bi_f, const float* __restrict__ bh_f,
    const float* __restrict__ bi_r, const float* __restrict__ bh_r,
    u16* __restrict__ x1) {
  __shared__ __align__(16) u16 apanel_hi[16][392];  // [m][k] 0:128=x_t 128:384=h
  __shared__ __align__(16) u16 apanel_lo[16][392];
  __shared__ float gbuf[4][16][257];                // [gate][m][j]

  const int tid = threadIdx.x;
  const int lane = tid & 63;
  const int wv = tid >> 6;
  const int gate = wv & 3;
  const int nh = wv >> 2;
  const int dir = blockIdx.x >> 5;
  const int b0 = (blockIdx.x & 31) * 16;
  const u16* wts = wt + dir * (1024 * 384);
  const float* bi = dir ? bi_r : bi_f;
  const float* bh = dir ? bh_r : bh_f;
  const int mrow = lane & 15, quad = lane >> 4;
  const int um = tid >> 5, uj = tid & 31;

  float c[8];
  float bias0[8], bias1[8], bias2[8], bias3[8];
#pragma unroll
  for (int i = 0; i < 8; ++i) {
    c[i] = 0.f;
    int j = uj + 32 * i;
    bias0[i] = bi[0 * 256 + j] + bh[0 * 256 + j];
    bias1[i] = bi[1 * 256 + j] + bh[1 * 256 + j];
    bias2[i] = bi[2 * 256 + j] + bh[2 * 256 + j];
    bias3[i] = bi[3 * 256 + j] + bh[3 * 256 + j];
  }
#pragma unroll
  for (int i = 0; i < 8; ++i) {
    int idx = tid + 512 * i;
    apanel_hi[idx >> 8][128 + (idx & 255)] = 0;
    apanel_lo[idx >> 8][128 + (idx & 255)] = 0;
  }

  const u16* wbase = wts + (gate * 256 + nh * 128 + mrow) * 384 + quad * 8;

  for (int t = 0; t < 128; ++t) {
    {
      int teff = dir ? (127 - t) : t;
      int row = tid >> 5, c4 = (tid & 31) * 4;
      const float* xp = x0 + (((b0 + row) * 128 + teff) << 7) + c4;
      float4 v = *(const float4*)xp;
      u16 h0 = f2h(v.x), h1 = f2h(v.y), h2 = f2h(v.z), h3 = f2h(v.w);
      ushort4 hv = {h0, h1, h2, h3};
      ushort4 lv = {f2h(v.x - h2f(h0)), f2h(v.y - h2f(h1)),
                    f2h(v.z - h2f(h2)), f2h(v.w - h2f(h3))};
      *(ushort4*)&apanel_hi[row][c4] = hv;
      *(ushort4*)&apanel_lo[row][c4] = lv;
    }
    __syncthreads();

    i16x8_t ah[12], al[12];
#pragma unroll
    for (int kb = 0; kb < 12; ++kb) {
      ah[kb] = *(const i16x8_t*)&apanel_hi[mrow][kb * 32 + quad * 8];
      al[kb] = *(const i16x8_t*)&apanel_lo[mrow][kb * 32 + quad * 8];
    }
#pragma unroll 2
    for (int nt = 0; nt < 8; ++nt) {
      const u16* wp = wbase + nt * (16 * 384);
      i16x8_t bfr[12];
#pragma unroll
      for (int kb = 0; kb < 12; ++kb)
        bfr[kb] = *(const i16x8_t*)(wp + kb * 32);
      f32x4_t acc = {0.f, 0.f, 0.f, 0.f};
#pragma unroll
      for (int kb = 0; kb < 12; ++kb) acc = mfma16h(ah[kb], bfr[kb], acc);
#pragma unroll
      for (int kb = 0; kb < 12; ++kb) acc = mfma16h(al[kb], bfr[kb], acc);
      int jc = nh * 128 + nt * 16 + mrow;
#pragma unroll
      for (int r = 0; r < 4; ++r) gbuf[gate][quad * 4 + r][jc] = acc[r];
    }
    __syncthreads();

#pragma unroll
    for (int i = 0; i < 8; ++i) {
      int j = uj + 32 * i;
      float fg = gbuf[0][um][j] + bias0[i];
      float ig = gbuf[1][um][j] + bias1[i];
      float ag = gbuf[2][um][j] + bias2[i];
      float og = gbuf[3][um][j] + bias3[i];
      float cv = sigmoidf_(fg) * c[i] + sigmoidf_(ig) * tanhf_(ag);
      c[i] = cv;
      float hv = sigmoidf_(og) * tanhf_(cv);
      u16 hhi = f2h(hv);
      apanel_hi[um][128 + j] = hhi;
      apanel_lo[um][128 + j] = f2h(hv - h2f(hhi));
      x1[(((b0 + um) << 7) + t) * 512 + dir * 256 + j] = hhi;
    }
  }
}

// ---- fused MLP + heads, TRUE dims (hidden = 256) ---------------------------
// 512 blocks x 128 rows, 512 threads = 8 waves, wave wv = m-tile wv.
__global__ __launch_bounds__(512, 1) void mlp_kernel(
    const u16* __restrict__ x1, const u16* __restrict__ w1t,
    const u16* __restrict__ w2t, const u16* __restrict__ w3t,
    const float* __restrict__ b1, const float* __restrict__ b2,
    const float* __restrict__ b3, float* __restrict__ out) {
  __shared__ __align__(16) u16 X2[128][264];
  __shared__ __align__(16) u16 X3[128][264];
  const int tid = threadIdx.x;
  const int lane = tid & 63, wv = tid >> 6;
  const int mrow = lane & 15, quad = lane >> 4;
  const int r0 = blockIdx.x * 128;
  const f32x4_t zero4 = {0.f, 0.f, 0.f, 0.f};

  // stage 1: X2[128][256] = leaky(x1[128,512] @ W1 + b1)
  {
    f32x4_t acc[16];
#pragma unroll
    for (int n = 0; n < 16; ++n) acc[n] = zero4;
    for (int kb = 0; kb < 16; ++kb) {
      int k = kb * 32 + quad * 8;
      i16x8_t a = *(const i16x8_t*)(x1 + (size_t)(r0 + wv * 16 + mrow) * 512 + k);
#pragma unroll
      for (int n = 0; n < 16; ++n) {
        i16x8_t b = *(const i16x8_t*)(w1t + (n * 16 + mrow) * 512 + k);
        acc[n] = mfma16h(a, b, acc[n]);
      }
    }
#pragma unroll
    for (int n = 0; n < 16; ++n)
#pragma unroll
      for (int r = 0; r < 4; ++r) {
        int m = wv * 16 + quad * 4 + r;
        int col = n * 16 + mrow;
        float v = acc[n][r] + b1[col];
        v = v > 0.f ? v : 0.1f * v;
        X2[m][col] = f2h(v);
      }
  }
  __syncthreads();

  // stage 2: X3[128][256] = leaky(X2 @ W2 + b2), K=256
  {
    f32x4_t acc[16];
#pragma unroll
    for (int n = 0; n < 16; ++n) acc[n] = zero4;
#pragma unroll
    for (int kb = 0; kb < 8; ++kb) {
      int k = kb * 32 + quad * 8;
      i16x8_t a = *(const i16x8_t*)&X2[wv * 16 + mrow][k];
#pragma unroll
      for (int n = 0; n < 16; ++n) {
        i16x8_t b = *(const i16x8_t*)(w2t + (n * 16 + mrow) * 256 + k);
        acc[n] = mfma16h(a, b, acc[n]);
      }
    }
#pragma unroll
    for (int n = 0; n < 16; ++n)
#pragma unroll
      for (int r = 0; r < 4; ++r) {
        int m = wv * 16 + quad * 4 + r;
        int col = n * 16 + mrow;
        float v = acc[n][r] + b2[col];
        v = v > 0.f ? v : 0.1f * v;
        X3[m][col] = f2h(v);
      }
  }
  __syncthreads();

  // stage 3: XF[128][128] = X3 @ W3 + b3 (fp32; XF overlays dead X2)
  float (*XF)[130] = (float (*)[130]) & X2[0][0];
  {
    f32x4_t acc[8];
#pragma unroll
    for (int n = 0; n < 8; ++n) acc[n] = zero4;
#pragma unroll
    for (int kb = 0; kb < 8; ++kb) {
      int k = kb * 32 + quad * 8;
      i16x8_t a = *(const i16x8_t*)&X3[wv * 16 + mrow][k];
#pragma unroll
      for (int n = 0; n < 8; ++n) {
        i16x8_t b = *(const i16x8_t*)(w3t + (n * 16 + mrow) * 256 + k);
        acc[n] = mfma16h(a, b, acc[n]);
      }
    }
#pragma unroll
    for (int n = 0; n < 8; ++n)
#pragma unroll
      for (int r = 0; r < 4; ++r) {
        int m = wv * 16 + quad * 4 + r;
        int col = n * 16 + mrow;
        XF[m][col] = acc[n][r] + b3[col];
      }
  }
  __syncthreads();

  // heads: cols 0:64 sigmoid; softmax over [64,72), [72,88), [88,128)
  if (tid < 128) {
    int row = tid;
    float* xr = XF[row];
    float* op = out + (size_t)(r0 + row) * 128;
    for (int cc = 0; cc < 64; ++cc) op[cc] = sigmoidf_(xr[cc]);
  } else if (tid < 256) {
    int row = tid - 128;
    float* xr = XF[row];
    float* op = out + (size_t)(r0 + row) * 128;
    const int s0s[3] = {64, 72, 88};
    const int s1s[3] = {72, 88, 128};
    for (int s = 0; s < 3; ++s) {
      int s0 = s0s[s], s1 = s1s[s];
      float mx = xr[s0];
      for (int q = s0 + 1; q < s1; ++q) mx = fmaxf(mx, xr[q]);
      float sum = 0.f;
      for (int q = s0; q < s1; ++q) { float e = __expf(xr[q] - mx); xr[q] = e; sum += e; }
      float inv = 1.f / sum;
      for (int q = s0; q < s1; ++q) op[q] = xr[q] * inv;
    }
  }
}

// ---- launch ----------------------------------------------------------------
extern "C" void kernel_launch(void* const* d_in, const int* in_sizes, int n_in,
                              void* d_out, int out_size, void* d_ws, size_t ws_size,
                              hipStream_t stream) {
  const float* x0   = (const float*)d_in[0];
  const float* Wi_f = (const float*)d_in[1];
  const float* bi_f = (const float*)d_in[2];
  const float* Wh_f = (const float*)d_in[3];
  const float* bh_f = (const float*)d_in[4];
  const float* Wi_r = (const float*)d_in[5];
  const float* bi_r = (const float*)d_in[6];
  const float* Wh_r = (const float*)d_in[7];
  const float* bh_r = (const float*)d_in[8];
  const float* W1 = (const float*)d_in[9];
  const float* b1 = (const float*)d_in[10];
  const float* W2 = (const float*)d_in[11];
  const float* b2 = (const float*)d_in[12];
  const float* W3 = (const float*)d_in[13];
  const float* b3 = (const float*)d_in[14];
  float* out = (float*)d_out;

  char* ws = (char*)d_ws;
  u16* w1t = (u16*)(ws + 0);         // 256*512*2  = 262144 B
  u16* w2t = (u16*)(ws + 262144);    // 256*256*2  = 131072 B
  u16* w3t = (u16*)(ws + 393216);    // 128*256*2  = 65536 B
  u16* wt  = (u16*)(ws + 458752);    // 2*1024*384*2 = 1572864 B
  u16* x1  = (u16*)(ws + 2031616);   // 65536*512*2 = 67108864 B

  hipLaunchKernelGGL(prep_wt, dim3(3072), dim3(256), 0, stream,
                     Wi_f, Wh_f, Wi_r, Wh_r, wt);
  hipLaunchKernelGGL(prep_small, dim3(896), dim3(256), 0, stream,
                     W1, W2, W3, w1t, w2t, w3t);
  hipLaunchKernelGGL(lstm_kernel, dim3(64), dim3(512), 0, stream,
                     x0, wt, bi_f, bh_f, bi_r, bh_r, x1);
  hipLaunchKernelGGL(mlp_kernel, dim3(512), dim3(512), 0, stream,
                     x1, w1t, w2t, w3t, b1, b2, b3, out);
}

// Round 5
// 2353.606 us; speedup vs baseline: 1.4797x; 1.4797x over previous
//
#include <hip/hip_runtime.h>

typedef unsigned short u16;
typedef _Float16 f16x8_t __attribute__((ext_vector_type(8)));
typedef short    i16x8_t __attribute__((ext_vector_type(8)));
typedef float    f32x4_t __attribute__((ext_vector_type(4)));

// ---- helpers ---------------------------------------------------------------
static __device__ __forceinline__ u16 f2h(float f) {
  _Float16 h = (_Float16)f;  // RNE
  return __builtin_bit_cast(u16, h);
}
static __device__ __forceinline__ f32x4_t mfma16h(i16x8_t a, i16x8_t b, f32x4_t c) {
  return __builtin_amdgcn_mfma_f32_16x16x32_f16(
      __builtin_bit_cast(f16x8_t, a), __builtin_bit_cast(f16x8_t, b), c, 0, 0, 0);
}
static __device__ __forceinline__ float sigmoidf_(float x) { return 1.f / (1.f + __expf(-x)); }
static __device__ __forceinline__ float tanhf_(float x) { return 1.f - 2.f / (__expf(2.f * x) + 1.f); }

// ---- prep: LSTM W^T in f16 -------------------------------------------------
// wt: [dir][n=1024][k=384], k<128 -> Wi[k][n], k>=128 -> Wh[k-128][n]
__global__ __launch_bounds__(256) void prep_wt(const float* __restrict__ Wi_f,
                                               const float* __restrict__ Wh_f,
                                               const float* __restrict__ Wi_r,
                                               const float* __restrict__ Wh_r,
                                               u16* __restrict__ wt) {
  int id = blockIdx.x * 256 + threadIdx.x;
  if (id >= 2 * 1024 * 384) return;
  int d = id / (1024 * 384);
  int r = id % (1024 * 384);
  int n = r / 384, k = r % 384;
  const float* Wi = d ? Wi_r : Wi_f;
  const float* Wh = d ? Wh_r : Wh_f;
  float v = (k < 128) ? Wi[k * 1024 + n] : Wh[(k - 128) * 1024 + n];
  wt[id] = f2h(v);
}

// ---- prep: MLP W^T in f16 (W1[512][256], W2[256][256], W3[256][128]) -------
__global__ __launch_bounds__(256) void prep_small(const float* __restrict__ W1,
                                                  const float* __restrict__ W2,
                                                  const float* __restrict__ W3,
                                                  u16* __restrict__ w1t,
                                                  u16* __restrict__ w2t,
                                                  u16* __restrict__ w3t) {
  int id = blockIdx.x * 256 + threadIdx.x;
  if (id < 131072) { int n = id >> 9, k = id & 511; w1t[id] = f2h(W1[k * 256 + n]); return; }
  id -= 131072;
  if (id < 65536) { int n = id >> 8, k = id & 255; w2t[id] = f2h(W2[k * 256 + n]); return; }
  id -= 65536;
  if (id < 32768) { int n = id >> 8, k = id & 255; w3t[id] = f2h(W3[k * 128 + n]); }
}

// ---- bidirectional LSTM v2 -------------------------------------------------
// 64 blocks (32/dir, M=16), 512 threads = 8 waves. Wave w owns j-blocks
// {w, w+8} (16 cols each) x ALL 4 gates -> in-register f/i/a/o update.
// Single fp16 path. Double-buffered x/h LDS panels -> ONE barrier per step.
// Weight tiles streamed from L2 with a 1-tile register prefetch pipeline.
__global__ __launch_bounds__(512, 2) void lstm_kernel(
    const float* __restrict__ x0, const u16* __restrict__ wt,
    const float* __restrict__ bi_f, const float* __restrict__ bh_f,
    const float* __restrict__ bi_r, const float* __restrict__ bh_r,
    u16* __restrict__ x1) {
  __shared__ __align__(16) u16 ax[2][16][136];   // x_t panel, [par][m][k<128]
  __shared__ __align__(16) u16 ah[2][16][264];   // h panel,   [par][m][j<256]

  const int tid = threadIdx.x;
  const int lane = tid & 63;
  const int w = tid >> 6;               // wave id = base j-block
  const int dir = blockIdx.x >> 5;
  const int b0 = (blockIdx.x & 31) * 16;
  const u16* wts = wt + dir * (1024 * 384);
  const float* bi = dir ? bi_r : bi_f;
  const float* bh = dir ? bh_r : bh_f;
  const int mrow = lane & 15, quad = lane >> 4;
  const int srow = tid >> 5, sc4 = (tid & 31) * 4;  // x-stage mapping
  const int fm = tid >> 5, fj = (tid & 31) * 8;     // x1-flush mapping

  // per-lane bias for (jbsel, gate) at j = (w + 8*jbsel)*16 + mrow
  float bias_[2][4];
#pragma unroll
  for (int jb = 0; jb < 2; ++jb)
#pragma unroll
    for (int g = 0; g < 4; ++g) {
      int j = (w + 8 * jb) * 16 + mrow;
      bias_[jb][g] = bi[g * 256 + j] + bh[g * 256 + j];
    }

  float c[2][4];
#pragma unroll
  for (int jb = 0; jb < 2; ++jb)
#pragma unroll
    for (int r = 0; r < 4; ++r) c[jb][r] = 0.f;

  // zero both h buffers (h_{-1} = 0)
  for (int i = tid; i < 2 * 16 * 264; i += 512)
    ((u16*)ah)[i] = 0;

  // weight base: row n = w*16 + mrow, col offset quad*8
  const u16* wrow = wts + (w * 16 + mrow) * 384 + quad * 8;
  // tile offsets: gate -> +g*256*384, jbsel -> +8*16*384
  const int GOFF = 256 * 384, JOFF = 8 * 16 * 384;

  i16x8_t wb0[12], wb1[12];
  // prime tile 0 (jbsel 0, gate 0)
#pragma unroll
  for (int kb = 0; kb < 12; ++kb)
    wb0[kb] = *(const i16x8_t*)(wrow + kb * 32);

  for (int t = 0; t < 128; ++t) {
    const int par = t & 1;
    // stage x_t -> ax[par]
    {
      int teff = dir ? (127 - t) : t;
      const float* xp = x0 + (((b0 + srow) * 128 + teff) << 7) + sc4;
      float4 v = *(const float4*)xp;
      ushort4 hv = {f2h(v.x), f2h(v.y), f2h(v.z), f2h(v.w)};
      *(ushort4*)&ax[par][srow][sc4] = hv;
    }
    __syncthreads();  // orders: x stage, prev update h-writes, prev flush reads

    // coalesced flush of h_{t-1} -> x1
    if (t > 0) {
      i16x8_t hh = *(const i16x8_t*)&ah[par ^ 1][fm][fj];
      *(i16x8_t*)(x1 + (size_t)(((b0 + fm) << 7) + (t - 1)) * 512 + dir * 256 + fj) = hh;
    }

    // a-fragments for this step (x_t | h_{t-1})
    i16x8_t af[12];
#pragma unroll
    for (int kb = 0; kb < 4; ++kb)
      af[kb] = *(const i16x8_t*)&ax[par][mrow][kb * 32 + quad * 8];
#pragma unroll
    for (int kb = 4; kb < 12; ++kb)
      af[kb] = *(const i16x8_t*)&ah[par ^ 1][mrow][(kb - 4) * 32 + quad * 8];

    f32x4_t acc[4];
#pragma unroll
    for (int tau = 0; tau < 8; ++tau) {
      const int g = tau & 3;
      // issue loads for tile tau+1 (mod 8) into the other buffer
      {
        const int ntau = (tau + 1) & 7;
        const int njb = ntau >> 2, ng = ntau & 3;
        const u16* np = wrow + ng * GOFF + njb * JOFF;
        i16x8_t* nb = (tau & 1) ? wb0 : wb1;
#pragma unroll
        for (int kb = 0; kb < 12; ++kb)
          nb[kb] = *(const i16x8_t*)(np + kb * 32);
      }
      // consume current buffer
      {
        const i16x8_t* cb = (tau & 1) ? wb1 : wb0;
        f32x4_t a = {0.f, 0.f, 0.f, 0.f};
#pragma unroll
        for (int kb = 0; kb < 12; ++kb) a = mfma16h(af[kb], cb[kb], a);
        acc[g] = a;
      }
      if (g == 3) {
        const int jb = tau >> 2;
        const int j = (w + 8 * jb) * 16 + mrow;
#pragma unroll
        for (int r = 0; r < 4; ++r) {
          float fg = acc[0][r] + bias_[jb][0];
          float ig = acc[1][r] + bias_[jb][1];
          float ag = acc[2][r] + bias_[jb][2];
          float og = acc[3][r] + bias_[jb][3];
          float cv = sigmoidf_(fg) * c[jb][r] + sigmoidf_(ig) * tanhf_(ag);
          c[jb][r] = cv;
          float hv = sigmoidf_(og) * tanhf_(cv);
          ah[par][quad * 4 + r][j] = f2h(hv);
        }
      }
    }
  }
  // epilogue: flush h_127 (in ah[127&1 = 1])
  __syncthreads();
  {
    i16x8_t hh = *(const i16x8_t*)&ah[1][fm][fj];
    *(i16x8_t*)(x1 + (size_t)(((b0 + fm) << 7) + 127) * 512 + dir * 256 + fj) = hh;
  }
}

// ---- fused MLP + heads (unchanged from round 4 — passing) ------------------
__global__ __launch_bounds__(512, 1) void mlp_kernel(
    const u16* __restrict__ x1, const u16* __restrict__ w1t,
    const u16* __restrict__ w2t, const u16* __restrict__ w3t,
    const float* __restrict__ b1, const float* __restrict__ b2,
    const float* __restrict__ b3, float* __restrict__ out) {
  __shared__ __align__(16) u16 X2[128][264];
  __shared__ __align__(16) u16 X3[128][264];
  const int tid = threadIdx.x;
  const int lane = tid & 63, wv = tid >> 6;
  const int mrow = lane & 15, quad = lane >> 4;
  const int r0 = blockIdx.x * 128;
  const f32x4_t zero4 = {0.f, 0.f, 0.f, 0.f};

  // stage 1: X2[128][256] = leaky(x1[128,512] @ W1 + b1)
  {
    f32x4_t acc[16];
#pragma unroll
    for (int n = 0; n < 16; ++n) acc[n] = zero4;
    for (int kb = 0; kb < 16; ++kb) {
      int k = kb * 32 + quad * 8;
      i16x8_t a = *(const i16x8_t*)(x1 + (size_t)(r0 + wv * 16 + mrow) * 512 + k);
#pragma unroll
      for (int n = 0; n < 16; ++n) {
        i16x8_t b = *(const i16x8_t*)(w1t + (n * 16 + mrow) * 512 + k);
        acc[n] = mfma16h(a, b, acc[n]);
      }
    }
#pragma unroll
    for (int n = 0; n < 16; ++n)
#pragma unroll
      for (int r = 0; r < 4; ++r) {
        int m = wv * 16 + quad * 4 + r;
        int col = n * 16 + mrow;
        float v = acc[n][r] + b1[col];
        v = v > 0.f ? v : 0.1f * v;
        X2[m][col] = f2h(v);
      }
  }
  __syncthreads();

  // stage 2: X3[128][256] = leaky(X2 @ W2 + b2), K=256
  {
    f32x4_t acc[16];
#pragma unroll
    for (int n = 0; n < 16; ++n) acc[n] = zero4;
#pragma unroll
    for (int kb = 0; kb < 8; ++kb) {
      int k = kb * 32 + quad * 8;
      i16x8_t a = *(const i16x8_t*)&X2[wv * 16 + mrow][k];
#pragma unroll
      for (int n = 0; n < 16; ++n) {
        i16x8_t b = *(const i16x8_t*)(w2t + (n * 16 + mrow) * 256 + k);
        acc[n] = mfma16h(a, b, acc[n]);
      }
    }
#pragma unroll
    for (int n = 0; n < 16; ++n)
#pragma unroll
      for (int r = 0; r < 4; ++r) {
        int m = wv * 16 + quad * 4 + r;
        int col = n * 16 + mrow;
        float v = acc[n][r] + b2[col];
        v = v > 0.f ? v : 0.1f * v;
        X3[m][col] = f2h(v);
      }
  }
  __syncthreads();

  // stage 3: XF[128][128] = X3 @ W3 + b3 (fp32; overlays dead X2)
  float (*XF)[130] = (float (*)[130]) & X2[0][0];
  {
    f32x4_t acc[8];
#pragma unroll
    for (int n = 0; n < 8; ++n) acc[n] = zero4;
#pragma unroll
    for (int kb = 0; kb < 8; ++kb) {
      int k = kb * 32 + quad * 8;
      i16x8_t a = *(const i16x8_t*)&X3[wv * 16 + mrow][k];
#pragma unroll
      for (int n = 0; n < 8; ++n) {
        i16x8_t b = *(const i16x8_t*)(w3t + (n * 16 + mrow) * 256 + k);
        acc[n] = mfma16h(a, b, acc[n]);
      }
    }
#pragma unroll
    for (int n = 0; n < 8; ++n)
#pragma unroll
      for (int r = 0; r < 4; ++r) {
        int m = wv * 16 + quad * 4 + r;
        int col = n * 16 + mrow;
        XF[m][col] = acc[n][r] + b3[col];
      }
  }
  __syncthreads();

  // heads: cols 0:64 sigmoid; softmax over [64,72), [72,88), [88,128)
  if (tid < 128) {
    int row = tid;
    float* xr = XF[row];
    float* op = out + (size_t)(r0 + row) * 128;
    for (int cc = 0; cc < 64; ++cc) op[cc] = sigmoidf_(xr[cc]);
  } else if (tid < 256) {
    int row = tid - 128;
    float* xr = XF[row];
    float* op = out + (size_t)(r0 + row) * 128;
    const int s0s[3] = {64, 72, 88};
    const int s1s[3] = {72, 88, 128};
    for (int s = 0; s < 3; ++s) {
      int s0 = s0s[s], s1 = s1s[s];
      float mx = xr[s0];
      for (int q = s0 + 1; q < s1; ++q) mx = fmaxf(mx, xr[q]);
      float sum = 0.f;
      for (int q = s0; q < s1; ++q) { float e = __expf(xr[q] - mx); xr[q] = e; sum += e; }
      float inv = 1.f / sum;
      for (int q = s0; q < s1; ++q) op[q] = xr[q] * inv;
    }
  }
}

// ---- launch ----------------------------------------------------------------
extern "C" void kernel_launch(void* const* d_in, const int* in_sizes, int n_in,
                              void* d_out, int out_size, void* d_ws, size_t ws_size,
                              hipStream_t stream) {
  const float* x0   = (const float*)d_in[0];
  const float* Wi_f = (const float*)d_in[1];
  const float* bi_f = (const float*)d_in[2];
  const float* Wh_f = (const float*)d_in[3];
  const float* bh_f = (const float*)d_in[4];
  const float* Wi_r = (const float*)d_in[5];
  const float* bi_r = (const float*)d_in[6];
  const float* Wh_r = (const float*)d_in[7];
  const float* bh_r = (const float*)d_in[8];
  const float* W1 = (const float*)d_in[9];
  const float* b1 = (const float*)d_in[10];
  const float* W2 = (const float*)d_in[11];
  const float* b2 = (const float*)d_in[12];
  const float* W3 = (const float*)d_in[13];
  const float* b3 = (const float*)d_in[14];
  float* out = (float*)d_out;

  char* ws = (char*)d_ws;
  u16* w1t = (u16*)(ws + 0);         // 262144 B
  u16* w2t = (u16*)(ws + 262144);    // 131072 B
  u16* w3t = (u16*)(ws + 393216);    // 65536 B
  u16* wt  = (u16*)(ws + 458752);    // 1572864 B
  u16* x1  = (u16*)(ws + 2031616);   // 67108864 B

  hipLaunchKernelGGL(prep_wt, dim3(3072), dim3(256), 0, stream,
                     Wi_f, Wh_f, Wi_r, Wh_r, wt);
  hipLaunchKernelGGL(prep_small, dim3(896), dim3(256), 0, stream,
                     W1, W2, W3, w1t, w2t, w3t);
  hipLaunchKernelGGL(lstm_kernel, dim3(64), dim3(512), 0, stream,
                     x0, wt, bi_f, bh_f, bi_r, bh_r, x1);
  hipLaunchKernelGGL(mlp_kernel, dim3(512), dim3(512), 0, stream,
                     x1, w1t, w2t, w3t, b1, b2, b3, out);
}

// Round 6
// 1894.081 us; speedup vs baseline: 1.8387x; 1.2426x over previous
//
#include <hip/hip_runtime.h>

typedef unsigned short u16;
typedef _Float16 f16x8_t __attribute__((ext_vector_type(8)));
typedef short    i16x8_t __attribute__((ext_vector_type(8)));
typedef short    i16x4_t __attribute__((ext_vector_type(4)));
typedef float    f32x4_t __attribute__((ext_vector_type(4)));

// ---- helpers ---------------------------------------------------------------
static __device__ __forceinline__ u16 f2h(float f) {
  _Float16 h = (_Float16)f;  // RNE
  return __builtin_bit_cast(u16, h);
}
static __device__ __forceinline__ f32x4_t mfma16h(i16x8_t a, i16x8_t b, f32x4_t c) {
  return __builtin_amdgcn_mfma_f32_16x16x32_f16(
      __builtin_bit_cast(f16x8_t, a), __builtin_bit_cast(f16x8_t, b), c, 0, 0, 0);
}
static __device__ __forceinline__ float sigmoidf_(float x) { return 1.f / (1.f + __expf(-x)); }
static __device__ __forceinline__ float tanhf_(float x) { return 1.f - 2.f / (__expf(2.f * x) + 1.f); }

// ---- prep: LSTM weights pre-swizzled into MFMA fragment order --------------
// wpack[dir][tau][kb][lane][8]: tau = jb*4+g (jb = j-block, g = gate),
// kb in [0,12), lane = quad*16+mrow. Element e: n = g*256+jb*16+mrow,
// k = kb*32+quad*8+e; value = k<128 ? Wi[k][n] : Wh[k-128][n].
__global__ __launch_bounds__(256) void prep_wpack(const float* __restrict__ Wi_f,
                                                  const float* __restrict__ Wh_f,
                                                  const float* __restrict__ Wi_r,
                                                  const float* __restrict__ Wh_r,
                                                  u16* __restrict__ wpack) {
  int id = blockIdx.x * 256 + threadIdx.x;
  if (id >= 786432) return;  // 2*64*12*64*8
  int e = id & 7, r = id >> 3;
  int lane = r & 63; r >>= 6;
  int kb = r % 12; r /= 12;
  int tau = r & 63, dir = r >> 6;
  int mrow = lane & 15, quad = lane >> 4;
  int jb = tau >> 2, g = tau & 3;
  int n = g * 256 + jb * 16 + mrow;
  int k = kb * 32 + quad * 8 + e;
  const float* Wi = dir ? Wi_r : Wi_f;
  const float* Wh = dir ? Wh_r : Wh_f;
  float v = (k < 128) ? Wi[k * 1024 + n] : Wh[(k - 128) * 1024 + n];
  wpack[id] = f2h(v);
}

// ---- prep: MLP W^T in f16 (W1[512][256], W2[256][256], W3[256][128]) -------
__global__ __launch_bounds__(256) void prep_small(const float* __restrict__ W1,
                                                  const float* __restrict__ W2,
                                                  const float* __restrict__ W3,
                                                  u16* __restrict__ w1t,
                                                  u16* __restrict__ w2t,
                                                  u16* __restrict__ w3t) {
  int id = blockIdx.x * 256 + threadIdx.x;
  if (id < 131072) { int n = id >> 9, k = id & 511; w1t[id] = f2h(W1[k * 256 + n]); return; }
  id -= 131072;
  if (id < 65536) { int n = id >> 8, k = id & 255; w2t[id] = f2h(W2[k * 256 + n]); return; }
  id -= 65536;
  if (id < 32768) { int n = id >> 8, k = id & 255; w3t[id] = f2h(W3[k * 128 + n]); }
}

// ---- bidirectional LSTM v3 -------------------------------------------------
// 64 blocks (32/dir, M=16 batch rows), 1024 threads = 16 waves (4/SIMD).
// Wave w owns j-cols [w*16,(w+1)*16) x all 4 gates (tau = 4w+g) -> in-register
// f/i/a/o update, bias folded into acc init. kb<2 weight slice (128 KB) is
// LDS-resident; kb 2..11 streamed as fully-coalesced 1KB/wave frag loads.
__global__ __launch_bounds__(1024, 4) void lstm_kernel(
    const float* __restrict__ x0, const u16* __restrict__ wpack,
    const float* __restrict__ bi_f, const float* __restrict__ bh_f,
    const float* __restrict__ bi_r, const float* __restrict__ bh_r,
    u16* __restrict__ x1) {
  __shared__ __align__(16) u16 lw[64][2][64][8];   // 128 KB resident weights
  __shared__ __align__(16) u16 ax[2][16][136];     // x_t panel (f16)
  __shared__ __align__(16) u16 ah[2][16][264];     // h panel (f16)

  const int tid = threadIdx.x;
  const int lane = tid & 63;
  const int w = tid >> 6;               // wave id = j-block
  const int dir = blockIdx.x >> 5;
  const int b0 = (blockIdx.x & 31) * 16;
  const u16* wpk = wpack + (size_t)dir * (64 * 12 * 64 * 8);
  const float* bi = dir ? bi_r : bi_f;
  const float* bh = dir ? bh_r : bh_f;
  const int mrow = lane & 15, quad = lane >> 4;

  float bias_[4];
#pragma unroll
  for (int g = 0; g < 4; ++g) {
    int n = g * 256 + w * 16 + mrow;
    bias_[g] = bi[n] + bh[n];
  }
  float c[4] = {0.f, 0.f, 0.f, 0.f};

  // preload resident kb<2 weight slice: 8192 frags of 16 B
#pragma unroll
  for (int r = 0; r < 8; ++r) {
    int d = r * 1024 + tid;                 // frag index: tau*128 + kb*64 + lane
    int ltau = d >> 7, lkb = (d >> 6) & 1, llane = d & 63;
    i16x8_t v = *(const i16x8_t*)(wpk + (((size_t)ltau * 12 + lkb) * 64 + llane) * 8);
    *(i16x8_t*)&lw[ltau][lkb][llane][0] = v;
  }
  // h_{-1} = 0
  for (int i = tid; i < 2 * 16 * 264; i += 1024) ((u16*)ah)[i] = 0;

  const u16* wrow = wpk + lane * 8;

  for (int t = 0; t < 128; ++t) {
    const int par = t & 1;
    // stage x_t -> ax[par]: 16 rows x 128 cols, 2 floats/thread
    {
      int teff = dir ? (127 - t) : t;
      int row = tid >> 6, cc = (tid & 63) * 2;
      float2 v = *(const float2*)(x0 + (((b0 + row) * 128 + teff) << 7) + cc);
      ax[par][row][cc] = f2h(v.x);
      ax[par][row][cc + 1] = f2h(v.y);
    }
    __syncthreads();  // orders: x stage, preload (t=0), prev h-writes, flush reads

    // coalesced flush h_{t-1} -> x1 (8 B/thread)
    if (t > 0) {
      int fm = tid >> 6, fj = (tid & 63) * 4;
      i16x4_t hh = *(const i16x4_t*)&ah[par ^ 1][fm][fj];
      *(i16x4_t*)(x1 + ((size_t)((b0 + fm) * 128 + (t - 1))) * 512 + dir * 256 + fj) = hh;
    }

    // A-fragments: k<128 from x panel, k>=128 from h panel
    i16x8_t af[12];
#pragma unroll
    for (int kb = 0; kb < 4; ++kb)
      af[kb] = *(const i16x8_t*)&ax[par][mrow][kb * 32 + quad * 8];
#pragma unroll
    for (int kb = 4; kb < 12; ++kb)
      af[kb] = *(const i16x8_t*)&ah[par ^ 1][mrow][(kb - 4) * 32 + quad * 8];

    f32x4_t acc[4];
#pragma unroll
    for (int g = 0; g < 4; ++g) {
      const int tau = (w << 2) | g;
      const u16* wp = wrow + (size_t)tau * (12 * 512);
      i16x8_t wf[12];
      wf[0] = *(const i16x8_t*)&lw[tau][0][lane][0];
      wf[1] = *(const i16x8_t*)&lw[tau][1][lane][0];
#pragma unroll
      for (int kb = 2; kb < 12; ++kb)
        wf[kb] = *(const i16x8_t*)(wp + kb * 512);
      f32x4_t a = {bias_[g], bias_[g], bias_[g], bias_[g]};
#pragma unroll
      for (int kb = 0; kb < 12; ++kb) a = mfma16h(af[kb], wf[kb], a);
      acc[g] = a;
    }

    // in-register gate update; lane holds (m = quad*4+r, j = w*16+mrow)
    {
      const int jcol = (w << 4) | mrow;
#pragma unroll
      for (int r = 0; r < 4; ++r) {
        float cv = sigmoidf_(acc[0][r]) * c[r] + sigmoidf_(acc[1][r]) * tanhf_(acc[2][r]);
        c[r] = cv;
        float hv = sigmoidf_(acc[3][r]) * tanhf_(cv);
        ah[par][(quad << 2) | r][jcol] = f2h(hv);
      }
    }
  }
  // epilogue: flush h_127 (par of t=127 is 1)
  __syncthreads();
  {
    int fm = tid >> 6, fj = (tid & 63) * 4;
    i16x4_t hh = *(const i16x4_t*)&ah[1][fm][fj];
    *(i16x4_t*)(x1 + ((size_t)((b0 + fm) * 128 + 127)) * 512 + dir * 256 + fj) = hh;
  }
}

// ---- fused MLP + heads (unchanged from round 4 — passing) ------------------
__global__ __launch_bounds__(512, 1) void mlp_kernel(
    const u16* __restrict__ x1, const u16* __restrict__ w1t,
    const u16* __restrict__ w2t, const u16* __restrict__ w3t,
    const float* __restrict__ b1, const float* __restrict__ b2,
    const float* __restrict__ b3, float* __restrict__ out) {
  __shared__ __align__(16) u16 X2[128][264];
  __shared__ __align__(16) u16 X3[128][264];
  const int tid = threadIdx.x;
  const int lane = tid & 63, wv = tid >> 6;
  const int mrow = lane & 15, quad = lane >> 4;
  const int r0 = blockIdx.x * 128;
  const f32x4_t zero4 = {0.f, 0.f, 0.f, 0.f};

  // stage 1: X2[128][256] = leaky(x1[128,512] @ W1 + b1)
  {
    f32x4_t acc[16];
#pragma unroll
    for (int n = 0; n < 16; ++n) acc[n] = zero4;
    for (int kb = 0; kb < 16; ++kb) {
      int k = kb * 32 + quad * 8;
      i16x8_t a = *(const i16x8_t*)(x1 + (size_t)(r0 + wv * 16 + mrow) * 512 + k);
#pragma unroll
      for (int n = 0; n < 16; ++n) {
        i16x8_t b = *(const i16x8_t*)(w1t + (n * 16 + mrow) * 512 + k);
        acc[n] = mfma16h(a, b, acc[n]);
      }
    }
#pragma unroll
    for (int n = 0; n < 16; ++n)
#pragma unroll
      for (int r = 0; r < 4; ++r) {
        int m = wv * 16 + quad * 4 + r;
        int col = n * 16 + mrow;
        float v = acc[n][r] + b1[col];
        v = v > 0.f ? v : 0.1f * v;
        X2[m][col] = f2h(v);
      }
  }
  __syncthreads();

  // stage 2: X3[128][256] = leaky(X2 @ W2 + b2), K=256
  {
    f32x4_t acc[16];
#pragma unroll
    for (int n = 0; n < 16; ++n) acc[n] = zero4;
#pragma unroll
    for (int kb = 0; kb < 8; ++kb) {
      int k = kb * 32 + quad * 8;
      i16x8_t a = *(const i16x8_t*)&X2[wv * 16 + mrow][k];
#pragma unroll
      for (int n = 0; n < 16; ++n) {
        i16x8_t b = *(const i16x8_t*)(w2t + (n * 16 + mrow) * 256 + k);
        acc[n] = mfma16h(a, b, acc[n]);
      }
    }
#pragma unroll
    for (int n = 0; n < 16; ++n)
#pragma unroll
      for (int r = 0; r < 4; ++r) {
        int m = wv * 16 + quad * 4 + r;
        int col = n * 16 + mrow;
        float v = acc[n][r] + b2[col];
        v = v > 0.f ? v : 0.1f * v;
        X3[m][col] = f2h(v);
      }
  }
  __syncthreads();

  // stage 3: XF[128][128] = X3 @ W3 + b3 (fp32; overlays dead X2)
  float (*XF)[130] = (float (*)[130]) & X2[0][0];
  {
    f32x4_t acc[8];
#pragma unroll
    for (int n = 0; n < 8; ++n) acc[n] = zero4;
#pragma unroll
    for (int kb = 0; kb < 8; ++kb) {
      int k = kb * 32 + quad * 8;
      i16x8_t a = *(const i16x8_t*)&X3[wv * 16 + mrow][k];
#pragma unroll
      for (int n = 0; n < 8; ++n) {
        i16x8_t b = *(const i16x8_t*)(w3t + (n * 16 + mrow) * 256 + k);
        acc[n] = mfma16h(a, b, acc[n]);
      }
    }
#pragma unroll
    for (int n = 0; n < 8; ++n)
#pragma unroll
      for (int r = 0; r < 4; ++r) {
        int m = wv * 16 + quad * 4 + r;
        int col = n * 16 + mrow;
        XF[m][col] = acc[n][r] + b3[col];
      }
  }
  __syncthreads();

  // heads: cols 0:64 sigmoid; softmax over [64,72), [72,88), [88,128)
  if (tid < 128) {
    int row = tid;
    float* xr = XF[row];
    float* op = out + (size_t)(r0 + row) * 128;
    for (int cc = 0; cc < 64; ++cc) op[cc] = sigmoidf_(xr[cc]);
  } else if (tid < 256) {
    int row = tid - 128;
    float* xr = XF[row];
    float* op = out + (size_t)(r0 + row) * 128;
    const int s0s[3] = {64, 72, 88};
    const int s1s[3] = {72, 88, 128};
    for (int s = 0; s < 3; ++s) {
      int s0 = s0s[s], s1 = s1s[s];
      float mx = xr[s0];
      for (int q = s0 + 1; q < s1; ++q) mx = fmaxf(mx, xr[q]);
      float sum = 0.f;
      for (int q = s0; q < s1; ++q) { float e = __expf(xr[q] - mx); xr[q] = e; sum += e; }
      float inv = 1.f / sum;
      for (int q = s0; q < s1; ++q) op[q] = xr[q] * inv;
    }
  }
}

// ---- launch ----------------------------------------------------------------
extern "C" void kernel_launch(void* const* d_in, const int* in_sizes, int n_in,
                              void* d_out, int out_size, void* d_ws, size_t ws_size,
                              hipStream_t stream) {
  const float* x0   = (const float*)d_in[0];
  const float* Wi_f = (const float*)d_in[1];
  const float* bi_f = (const float*)d_in[2];
  const float* Wh_f = (const float*)d_in[3];
  const float* bh_f = (const float*)d_in[4];
  const float* Wi_r = (const float*)d_in[5];
  const float* bi_r = (const float*)d_in[6];
  const float* Wh_r = (const float*)d_in[7];
  const float* bh_r = (const float*)d_in[8];
  const float* W1 = (const float*)d_in[9];
  const float* b1 = (const float*)d_in[10];
  const float* W2 = (const float*)d_in[11];
  const float* b2 = (const float*)d_in[12];
  const float* W3 = (const float*)d_in[13];
  const float* b3 = (const float*)d_in[14];
  float* out = (float*)d_out;

  char* ws = (char*)d_ws;
  u16* w1t   = (u16*)(ws + 0);         // 262144 B
  u16* w2t   = (u16*)(ws + 262144);    // 131072 B
  u16* w3t   = (u16*)(ws + 393216);    // 65536 B
  u16* wpack = (u16*)(ws + 458752);    // 1572864 B
  u16* x1    = (u16*)(ws + 2031616);   // 67108864 B

  hipLaunchKernelGGL(prep_wpack, dim3(3072), dim3(256), 0, stream,
                     Wi_f, Wh_f, Wi_r, Wh_r, wpack);
  hipLaunchKernelGGL(prep_small, dim3(896), dim3(256), 0, stream,
                     W1, W2, W3, w1t, w2t, w3t);
  hipLaunchKernelGGL(lstm_kernel, dim3(64), dim3(1024), 0, stream,
                     x0, wpack, bi_f, bh_f, bi_r, bh_r, x1);
  hipLaunchKernelGGL(mlp_kernel, dim3(512), dim3(512), 0, stream,
                     x1, w1t, w2t, w3t, b1, b2, b3, out);
}